// Round 1
// baseline (270.907 us; speedup 1.0000x reference)
//
#include <hip/hip_runtime.h>

#define N 1681
#define BS 32
#define TI 41
#define NBANDS 41   // 41 * 41 = 1681 rows
#define THREADS 256
#define NK 7        // ceil(1681 / 256)

__global__ __launch_bounds__(THREADS) void pass1_kernel(
    const float* __restrict__ pred,
    const float* __restrict__ targ,
    float* __restrict__ sp,
    float* __restrict__ st,
    float* __restrict__ dcol) {
  __shared__ float red[8];

  const int bx   = blockIdx.x;
  const int l    = bx / NBANDS;
  const int band = bx % NBANDS;
  const int tid  = threadIdx.x;

  const size_t matbase = (size_t)l * ((size_t)N * (size_t)N);
  const int row0 = band * TI;

  float dacc[NK];
#pragma unroll
  for (int k = 0; k < NK; ++k) dacc[k] = 0.0f;

  for (int ir = 0; ir < TI; ++ir) {
    const int i = row0 + ir;
    const float* __restrict__ prow = pred + matbase + (size_t)i * N;
    const float* __restrict__ trow = targ + matbase + (size_t)i * N;

    float psq = 0.0f, tsq = 0.0f;
#pragma unroll
    for (int k = 0; k < NK; ++k) {
      const int j = tid + k * THREADS;
      if (j < N) {
        const float pv = prow[j];
        const float tv = trow[j];
        psq = fmaf(pv, pv, psq);
        tsq = fmaf(tv, tv, tsq);
        dacc[k] = fmaf(pv, tv, dacc[k]);
      }
    }

    // wave (64-lane) reduce, then cross-wave via LDS
#pragma unroll
    for (int off = 32; off > 0; off >>= 1) {
      psq += __shfl_down(psq, off, 64);
      tsq += __shfl_down(tsq, off, 64);
    }
    const int wid = tid >> 6;
    if ((tid & 63) == 0) { red[wid] = psq; red[4 + wid] = tsq; }
    __syncthreads();
    if (tid == 0) {
      sp[(size_t)l * N + i] = red[0] + red[1] + red[2] + red[3];
      st[(size_t)l * N + i] = red[4] + red[5] + red[6] + red[7];
    }
    __syncthreads();  // LDS reused next row
  }

#pragma unroll
  for (int k = 0; k < NK; ++k) {
    const int j = tid + k * THREADS;
    if (j < N) atomicAdd(&dcol[(size_t)l * N + j], dacc[k]);
  }
}

__global__ __launch_bounds__(THREADS) void finalize_kernel(
    const float* __restrict__ sp,
    const float* __restrict__ st,
    const float* __restrict__ dcol,
    float* __restrict__ out) {
  __shared__ double red[4];

  double acc = 0.0;
  for (int idx = threadIdx.x; idx < BS * N; idx += THREADS) {
    const double s = (double)sp[idx] * (double)st[idx];
    acc += (double)dcol[idx] / sqrt(s);
  }
#pragma unroll
  for (int off = 32; off > 0; off >>= 1) acc += __shfl_down(acc, off, 64);
  const int wid = threadIdx.x >> 6;
  if ((threadIdx.x & 63) == 0) red[wid] = acc;
  __syncthreads();
  if (threadIdx.x == 0) {
    const double t = red[0] + red[1] + red[2] + red[3];
    out[0] = (float)(-t / ((double)BS * (double)N));
  }
}

extern "C" void kernel_launch(void* const* d_in, const int* in_sizes, int n_in,
                              void* d_out, int out_size, void* d_ws, size_t ws_size,
                              hipStream_t stream) {
  const float* pred = (const float*)d_in[0];
  const float* targ = (const float*)d_in[1];

  float* ws   = (float*)d_ws;
  float* sp   = ws;                    // BS*N floats
  float* st   = ws + (size_t)BS * N;   // BS*N floats
  float* dcol = ws + (size_t)2 * BS * N; // BS*N floats

  // dcol is accumulated via atomics -> must be zeroed every call
  hipMemsetAsync(dcol, 0, (size_t)BS * N * sizeof(float), stream);

  pass1_kernel<<<BS * NBANDS, THREADS, 0, stream>>>(pred, targ, sp, st, dcol);
  finalize_kernel<<<1, THREADS, 0, stream>>>(sp, st, dcol, (float*)d_out);
}

// Round 2
// 172.140 us; speedup vs baseline: 1.5738x; 1.5738x over previous
//
#include <hip/hip_runtime.h>

#define N 1681
#define BS 32
#define BAND 41
#define NBLOCKS (BS * BAND)     // 1312
#define THREADS 256
#define NROWS_TOTAL (BS * N)    // 53792

// ws layout (floats): sp[53792] | st[53792] | dcol[53792] | bsums[64]

__global__ __launch_bounds__(THREADS) void zero_kernel(float* __restrict__ dcol) {
  const int idx = blockIdx.x * THREADS + threadIdx.x;
  if (idx < NROWS_TOTAL) dcol[idx] = 0.0f;
}

__global__ __launch_bounds__(THREADS) void pass1_kernel(
    const float* __restrict__ pred,
    const float* __restrict__ targ,
    float* __restrict__ sp,
    float* __restrict__ st,
    float* __restrict__ dcol) {
  __shared__ float dsum[N];

  const int b    = blockIdx.x;      // 0..1311
  const int tid  = threadIdx.x;
  const int lane = tid & 63;
  const int wid  = tid >> 6;        // 0..3; also the row alignment class h
  const int l    = b / BAND;        // matrix index (band never crosses a matrix: 1681 = 41*41)
  const long R0  = (long)b * BAND;  // first global row of this block

  for (int idx = tid; idx < N; idx += THREADS) dsum[idx] = 0.0f;
  __syncthreads();

  const float4* __restrict__ pred4 = (const float4*)pred;
  const float4* __restrict__ targ4 = (const float4*)targ;

  const int h = wid;                            // rows assigned so that (R & 3) == wid
  float dprod[7][4];
#pragma unroll
  for (int t2 = 0; t2 < 7; ++t2)
#pragma unroll
    for (int ee = 0; ee < 4; ++ee) dprod[t2][ee] = 0.0f;

  // first rr with (R0 + rr) & 3 == wid
  const int rr0 = (wid - (int)(R0 & 3)) & 3;

  for (int rr = rr0; rr < BAND; rr += 4) {
    const long R = R0 + rr;              // global row, R & 3 == h
    const long s = R * (long)N;          // flat start element; s & 3 == h
    const long q = s >> 2;               // first float4 chunk (row covers chunks q .. q+420)

    float psq = 0.0f, tsq = 0.0f;
#pragma unroll
    for (int t2 = 0; t2 < 7; ++t2) {
      const long c = q + t2 * 64 + lane;
      if (t2 < 6 || lane < 37) {         // 421 chunks per row (row-independent)
        const float4 p4 = pred4[c];
        const float4 t4 = targ4[c];
        const float pv[4] = {p4.x, p4.y, p4.z, p4.w};
        const float tv[4] = {t4.x, t4.y, t4.z, t4.w};
        if (t2 == 0 || t2 == 6) {
          // edge chunks: mask head (col<0) and tail (col>=N)
          const int colb = t2 * 256 + 4 * lane - h;
#pragma unroll
          for (int ee = 0; ee < 4; ++ee) {
            const bool ok = (unsigned)(colb + ee) < (unsigned)N;
            const float pm = ok ? pv[ee] : 0.0f;
            const float tm = ok ? tv[ee] : 0.0f;
            psq = fmaf(pm, pm, psq);
            tsq = fmaf(tm, tm, tsq);
            dprod[t2][ee] = fmaf(pm, tm, dprod[t2][ee]);
          }
        } else {
#pragma unroll
          for (int ee = 0; ee < 4; ++ee) {
            psq = fmaf(pv[ee], pv[ee], psq);
            tsq = fmaf(tv[ee], tv[ee], tsq);
            dprod[t2][ee] = fmaf(pv[ee], tv[ee], dprod[t2][ee]);
          }
        }
      }
    }

    // per-row wave reduce (no block barriers)
#pragma unroll
    for (int off = 32; off > 0; off >>= 1) {
      psq += __shfl_down(psq, off, 64);
      tsq += __shfl_down(tsq, off, 64);
    }
    if (lane == 0) {
      sp[R] = psq;
      st[R] = tsq;
    }
  }

  // fold per-wave register accumulators into LDS (column j of matrix l)
#pragma unroll
  for (int t2 = 0; t2 < 7; ++t2)
#pragma unroll
    for (int ee = 0; ee < 4; ++ee) {
      const int col = t2 * 256 + 4 * lane + ee - h;
      if ((unsigned)col < (unsigned)N) atomicAdd(&dsum[col], dprod[t2][ee]);
    }
  __syncthreads();

  for (int idx = tid; idx < N; idx += THREADS)
    atomicAdd(&dcol[(size_t)l * N + idx], dsum[idx]);
}

__global__ __launch_bounds__(THREADS) void fin1_kernel(
    const float* __restrict__ sp,
    const float* __restrict__ st,
    const float* __restrict__ dcol,
    float* __restrict__ bsums) {
  __shared__ double red[4];

  double acc = 0.0;
  for (int g = blockIdx.x * THREADS + threadIdx.x; g < NROWS_TOTAL;
       g += gridDim.x * THREADS) {
    const double s = (double)sp[g] * (double)st[g];
    acc += (double)dcol[g] / sqrt(s);
  }
#pragma unroll
  for (int off = 32; off > 0; off >>= 1) acc += __shfl_down(acc, off, 64);
  const int wid = threadIdx.x >> 6;
  if ((threadIdx.x & 63) == 0) red[wid] = acc;
  __syncthreads();
  if (threadIdx.x == 0)
    bsums[blockIdx.x] = (float)(red[0] + red[1] + red[2] + red[3]);
}

__global__ __launch_bounds__(64) void fin2_kernel(
    const float* __restrict__ bsums, float* __restrict__ out) {
  double acc = (double)bsums[threadIdx.x];
#pragma unroll
  for (int off = 32; off > 0; off >>= 1) acc += __shfl_down(acc, off, 64);
  if (threadIdx.x == 0)
    out[0] = (float)(-acc / ((double)BS * (double)N));
}

extern "C" void kernel_launch(void* const* d_in, const int* in_sizes, int n_in,
                              void* d_out, int out_size, void* d_ws, size_t ws_size,
                              hipStream_t stream) {
  const float* pred = (const float*)d_in[0];
  const float* targ = (const float*)d_in[1];

  float* ws    = (float*)d_ws;
  float* sp    = ws;
  float* st    = ws + (size_t)NROWS_TOTAL;
  float* dcol  = ws + (size_t)2 * NROWS_TOTAL;
  float* bsums = ws + (size_t)3 * NROWS_TOTAL;

  zero_kernel<<<(NROWS_TOTAL + THREADS - 1) / THREADS, THREADS, 0, stream>>>(dcol);
  pass1_kernel<<<NBLOCKS, THREADS, 0, stream>>>(pred, targ, sp, st, dcol);
  fin1_kernel<<<64, THREADS, 0, stream>>>(sp, st, dcol, bsums);
  fin2_kernel<<<1, 64, 0, stream>>>(bsums, (float*)d_out);
}

// Round 3
// 163.810 us; speedup vs baseline: 1.6538x; 1.0509x over previous
//
#include <hip/hip_runtime.h>

#define N 1681
#define BS 32
#define BAND 41
#define NBLOCKS (BS * BAND)     // 1312
#define THREADS 256
#define NROWS_TOTAL (BS * N)    // 53792

// ws layout (floats): sp[53792] | st[53792] | dcol[53792] | bsums[64]

__global__ __launch_bounds__(THREADS) void zero_kernel(float* __restrict__ dcol) {
  const int idx = blockIdx.x * THREADS + threadIdx.x;
  if (idx < NROWS_TOTAL) dcol[idx] = 0.0f;
}

__global__ __launch_bounds__(THREADS, 2) void pass1_kernel(
    const float* __restrict__ pred,
    const float* __restrict__ targ,
    float* __restrict__ sp,
    float* __restrict__ st,
    float* __restrict__ dcol) {
  __shared__ float dsum[N];

  const int b    = blockIdx.x;      // 0..1311
  const int tid  = threadIdx.x;
  const int lane = tid & 63;
  const int wid  = tid >> 6;        // 0..3; also the row alignment class h
  const int l    = b / BAND;        // matrix index (band never crosses a matrix)
  const long R0  = (long)b * BAND;  // first global row of this block

  for (int idx = tid; idx < N; idx += THREADS) dsum[idx] = 0.0f;
  __syncthreads();

  const float4* __restrict__ pred4 = (const float4*)pred;
  const float4* __restrict__ targ4 = (const float4*)targ;

  const int h = wid;                // rows assigned so that (R & 3) == wid
  float dprod[7][4];
#pragma unroll
  for (int t2 = 0; t2 < 7; ++t2)
#pragma unroll
    for (int ee = 0; ee < 4; ++ee) dprod[t2][ee] = 0.0f;

  float4 pA[7], tA[7], pB[7], tB[7];

#define LOADROW(PBUF, TBUF, RR) do {                                     \
    const long q_ = ((R0 + (RR)) * (long)N) >> 2;                        \
    _Pragma("unroll")                                                    \
    for (int t2 = 0; t2 < 7; ++t2) {                                     \
      if (t2 < 6 || lane < 37) {                                         \
        const long c_ = q_ + t2 * 64 + lane;                             \
        PBUF[t2] = pred4[c_];                                            \
        TBUF[t2] = targ4[c_];                                            \
      }                                                                  \
    }                                                                    \
  } while (0)

#define COMPROW(PBUF, TBUF, RR) do {                                     \
    const long R_ = R0 + (RR);                                           \
    float psq = 0.0f, tsq = 0.0f;                                        \
    _Pragma("unroll")                                                    \
    for (int t2 = 0; t2 < 7; ++t2) {                                     \
      const float pv[4] = {PBUF[t2].x, PBUF[t2].y, PBUF[t2].z, PBUF[t2].w}; \
      const float tv[4] = {TBUF[t2].x, TBUF[t2].y, TBUF[t2].z, TBUF[t2].w}; \
      if (t2 == 0 || t2 == 6) {                                          \
        const int colb = t2 * 256 + 4 * lane - h;                        \
        _Pragma("unroll")                                                \
        for (int ee = 0; ee < 4; ++ee) {                                 \
          const bool ok = (unsigned)(colb + ee) < (unsigned)N;           \
          const float pm = ok ? pv[ee] : 0.0f;                           \
          const float tm = ok ? tv[ee] : 0.0f;                           \
          psq = fmaf(pm, pm, psq);                                       \
          tsq = fmaf(tm, tm, tsq);                                       \
          dprod[t2][ee] = fmaf(pm, tm, dprod[t2][ee]);                   \
        }                                                                \
      } else {                                                           \
        _Pragma("unroll")                                                \
        for (int ee = 0; ee < 4; ++ee) {                                 \
          psq = fmaf(pv[ee], pv[ee], psq);                               \
          tsq = fmaf(tv[ee], tv[ee], tsq);                               \
          dprod[t2][ee] = fmaf(pv[ee], tv[ee], dprod[t2][ee]);           \
        }                                                                \
      }                                                                  \
    }                                                                    \
    _Pragma("unroll")                                                    \
    for (int off = 32; off > 0; off >>= 1) {                             \
      psq += __shfl_down(psq, off, 64);                                  \
      tsq += __shfl_down(tsq, off, 64);                                  \
    }                                                                    \
    if (lane == 0) { sp[R_] = psq; st[R_] = tsq; }                       \
  } while (0)

  // first rr with (R0 + rr) & 3 == wid
  const int rr0 = (wid - (int)(R0 & 3)) & 3;

  // 2-deep software pipeline: compute buffer X while buffer Y's loads fly
  int rr = rr0;
  LOADROW(pA, tA, rr);
  for (;;) {
    const int r1 = rr + 4;
    if (r1 < BAND) LOADROW(pB, tB, r1);
    COMPROW(pA, tA, rr);
    if (r1 >= BAND) break;
    const int r2 = r1 + 4;
    if (r2 < BAND) LOADROW(pA, tA, r2);
    COMPROW(pB, tB, r1);
    if (r2 >= BAND) break;
    rr = r2;
  }

  // fold per-wave register accumulators into LDS (column j of matrix l)
#pragma unroll
  for (int t2 = 0; t2 < 7; ++t2)
#pragma unroll
    for (int ee = 0; ee < 4; ++ee) {
      const int col = t2 * 256 + 4 * lane + ee - h;
      if ((unsigned)col < (unsigned)N) atomicAdd(&dsum[col], dprod[t2][ee]);
    }
  __syncthreads();

  for (int idx = tid; idx < N; idx += THREADS)
    atomicAdd(&dcol[(size_t)l * N + idx], dsum[idx]);
}

__global__ __launch_bounds__(THREADS) void fin1_kernel(
    const float* __restrict__ sp,
    const float* __restrict__ st,
    const float* __restrict__ dcol,
    float* __restrict__ bsums) {
  __shared__ double red[4];

  double acc = 0.0;
  for (int g = blockIdx.x * THREADS + threadIdx.x; g < NROWS_TOTAL;
       g += gridDim.x * THREADS) {
    const double s = (double)sp[g] * (double)st[g];
    acc += (double)dcol[g] / sqrt(s);
  }
#pragma unroll
  for (int off = 32; off > 0; off >>= 1) acc += __shfl_down(acc, off, 64);
  const int wid = threadIdx.x >> 6;
  if ((threadIdx.x & 63) == 0) red[wid] = acc;
  __syncthreads();
  if (threadIdx.x == 0)
    bsums[blockIdx.x] = (float)(red[0] + red[1] + red[2] + red[3]);
}

__global__ __launch_bounds__(64) void fin2_kernel(
    const float* __restrict__ bsums, float* __restrict__ out) {
  double acc = (double)bsums[threadIdx.x];
#pragma unroll
  for (int off = 32; off > 0; off >>= 1) acc += __shfl_down(acc, off, 64);
  if (threadIdx.x == 0)
    out[0] = (float)(-acc / ((double)BS * (double)N));
}

extern "C" void kernel_launch(void* const* d_in, const int* in_sizes, int n_in,
                              void* d_out, int out_size, void* d_ws, size_t ws_size,
                              hipStream_t stream) {
  const float* pred = (const float*)d_in[0];
  const float* targ = (const float*)d_in[1];

  float* ws    = (float*)d_ws;
  float* sp    = ws;
  float* st    = ws + (size_t)NROWS_TOTAL;
  float* dcol  = ws + (size_t)2 * NROWS_TOTAL;
  float* bsums = ws + (size_t)3 * NROWS_TOTAL;

  zero_kernel<<<(NROWS_TOTAL + THREADS - 1) / THREADS, THREADS, 0, stream>>>(dcol);
  pass1_kernel<<<NBLOCKS, THREADS, 0, stream>>>(pred, targ, sp, st, dcol);
  fin1_kernel<<<64, THREADS, 0, stream>>>(sp, st, dcol, bsums);
  fin2_kernel<<<1, 64, 0, stream>>>(bsums, (float*)d_out);
}